// Round 6
// baseline (357.157 us; speedup 1.0000x reference)
//
#include <hip/hip_runtime.h>

typedef __attribute__((ext_vector_type(8))) short short8;
typedef __attribute__((ext_vector_type(4))) short short4v;
typedef __attribute__((ext_vector_type(4))) float f32x4;

#define BATCH 65536
#define IN_DIM 784
#define HID 128
#define OUT_DIM 10
#define KPAD 800
#define NKS 25
#define BM 128
#define NBLK (BATCH / BM)

// workspace offsets (bytes), all 256-aligned
#define OFF_W1H 0
#define OFF_W1L 204800
#define OFF_W2S 409600
#define OFF_W3S 442368

__device__ __forceinline__ unsigned short bf16_rne(float f) {
    unsigned u = __float_as_uint(f);
    return (unsigned short)((u + 0x7FFFu + ((u >> 16) & 1u)) >> 16);
}
__device__ __forceinline__ float fast_tanh(float x) {
    float e = __expf(2.0f * x);
    return 1.0f - 2.0f / (e + 1.0f);
}

// Pre-pass: W1 -> k-padded (800), kstep-tiled [ks][col][32] bf16 hi/lo;
// W2 -> transposed [n][k] bf16; W3 -> transposed [j(pad16)][k] bf16.
__global__ void prep_kernel(const float* __restrict__ W1, const float* __restrict__ W2,
                            const float* __restrict__ W3,
                            unsigned short* __restrict__ w1h, unsigned short* __restrict__ w1l,
                            unsigned short* __restrict__ w2s, unsigned short* __restrict__ w3s) {
    int b = blockIdx.x, t = threadIdx.x;
    if (b < HID) {
        int col = b;
        for (int k = t; k < KPAD; k += 256) {
            float v = (k < IN_DIM) ? W1[k * HID + col] : 0.0f;
            unsigned u = __float_as_uint(v);
            unsigned short hi = (unsigned short)(u >> 16);       // trunc hi
            float hif = __uint_as_float(u & 0xFFFF0000u);
            unsigned short lo = bf16_rne(v - hif);               // rne lo
            int idx = ((k >> 5) * HID + col) * 32 + (k & 31);
            w1h[idx] = hi; w1l[idx] = lo;
        }
    } else if (b == HID) {
        for (int i = t; i < HID * HID; i += 256) {
            int n = i >> 7, k = i & 127;
            w2s[i] = bf16_rne(W2[k * HID + n]);
        }
    } else {
        for (int i = t; i < 16 * HID; i += 256) {
            int j = i >> 7, k = i & 127;
            float v = (j < OUT_DIM) ? W3[k * OUT_DIM + j] : 0.0f;
            w3s[i] = bf16_rne(v);
        }
    }
}

// Barrier-free design: W1 B-fragments are block-invariant -> loaded straight
// from global (L1/L2 broadcast); x A-fragments direct-to-reg with depth-1
// prefetch (no __syncthreads anywhere, so no vmcnt(0) drain kills it).
// ht is wave-row-private -> epilogue needs no barriers either.
__launch_bounds__(256, 3)
__global__ void fused_kernel(const float* __restrict__ X,
                             const float* __restrict__ b1,
                             const float* __restrict__ b2,
                             const float* __restrict__ ob,
                             const float* __restrict__ csc,
                             const unsigned short* __restrict__ w1h,
                             const unsigned short* __restrict__ w1l,
                             const unsigned short* __restrict__ w2s,
                             const unsigned short* __restrict__ w3s,
                             float* __restrict__ OUT) {
    __shared__ unsigned short ht[HID][136];   // transposed h/z, wave-private row slices

    const int t = threadIdx.x;
    const int wid = t >> 6, lane = t & 63;
    const int lg = lane >> 4, lr = lane & 15;
    const int row0 = blockIdx.x * BM;

    // GEMM1 accumulators init with bias1 (C/D layout: col=16f+lr, row=4*lg+r)
    f32x4 acc[2][8];
    #pragma unroll
    for (int f = 0; f < 8; ++f) {
        float bv = b1[16 * f + lr];
        f32x4 v = {bv, bv, bv, bv};
        acc[0][f] = v; acc[1][f] = v;
    }

    // x: each lane loads its own A-fragment bytes: rows wid*32+rf*16+lr, k = ks*32+8*lg..+8
    f32x4 xcur[2][2], xnxt[2][2];

    #define LOADX(dst, ks)                                                        \
        {                                                                         \
            int k0_ = (ks) * 32 + 8 * lg;                                         \
            _Pragma("unroll")                                                     \
            for (int rf = 0; rf < 2; ++rf) {                                      \
                f32x4 a_ = {0,0,0,0}, b_ = {0,0,0,0};                             \
                if (k0_ < IN_DIM) {                                               \
                    const f32x4* p_ = (const f32x4*)(X +                          \
                        (size_t)(row0 + wid * 32 + rf * 16 + lr) * IN_DIM + k0_); \
                    a_ = p_[0]; b_ = p_[1];                                       \
                }                                                                 \
                dst[rf][0] = a_; dst[rf][1] = b_;                                 \
            }                                                                     \
        }

    LOADX(xcur, 0);

    for (int ks = 0; ks < NKS; ++ks) {
        if (ks + 1 < NKS) LOADX(xnxt, ks + 1);   // stays in flight: no barrier below

        // split x into bf16 hi/lo in-register (trunc hi + rne lo)
        short8 xh[2], xl[2];
        #pragma unroll
        for (int rf = 0; rf < 2; ++rf) {
            short8 h8, l8;
            #pragma unroll
            for (int j = 0; j < 8; ++j) {
                float v = (j < 4) ? xcur[rf][0][j] : xcur[rf][1][j - 4];
                unsigned u = __float_as_uint(v);
                h8[j] = (short)(u >> 16);
                float lof = v - __uint_as_float(u & 0xFFFF0000u);
                l8[j] = (short)(__float_as_uint(lof) >> 16);
            }
            xh[rf] = h8; xl[rf] = l8;
        }

        // B fragments straight from global (pre-tiled [ks][col][32]; 1KB
        // contiguous per instr across the wave, identical for every wave/block)
        const unsigned short* whp = w1h + (size_t)ks * HID * 32 + 8 * lg;
        const unsigned short* wlp = w1l + (size_t)ks * HID * 32 + 8 * lg;
        #pragma unroll
        for (int f = 0; f < 8; ++f) {
            const short8 bh = *(const short8*)(whp + (16 * f + lr) * 32);
            const short8 bl = *(const short8*)(wlp + (16 * f + lr) * 32);
            acc[0][f] = __builtin_amdgcn_mfma_f32_16x16x32_bf16(xh[0], bh, acc[0][f], 0, 0, 0);
            acc[1][f] = __builtin_amdgcn_mfma_f32_16x16x32_bf16(xh[1], bh, acc[1][f], 0, 0, 0);
            acc[0][f] = __builtin_amdgcn_mfma_f32_16x16x32_bf16(xl[0], bh, acc[0][f], 0, 0, 0);
            acc[1][f] = __builtin_amdgcn_mfma_f32_16x16x32_bf16(xl[1], bh, acc[1][f], 0, 0, 0);
            acc[0][f] = __builtin_amdgcn_mfma_f32_16x16x32_bf16(xh[0], bl, acc[0][f], 0, 0, 0);
            acc[1][f] = __builtin_amdgcn_mfma_f32_16x16x32_bf16(xh[1], bl, acc[1][f], 0, 0, 0);
        }
        // rotate prefetch regs
        #pragma unroll
        for (int rf = 0; rf < 2; ++rf) { xcur[rf][0] = xnxt[rf][0]; xcur[rf][1] = xnxt[rf][1]; }
    }

    const float cs = csc[0];
    const float sgc = 1.0f / (1.0f + __expf(-cs));
    const float c = 0.001f * (0.5f + 1.5f * sgc);
    const float sc = sqrtf(c);

    // h = tanh(.), keep fp32 in acc; write bf16 transpose to ht (wave-private rows)
    #pragma unroll
    for (int rf = 0; rf < 2; ++rf) {
        const int rbase = wid * 32 + rf * 16 + 4 * lg;
        #pragma unroll
        for (int f = 0; f < 8; ++f) {
            short4v pk;
            #pragma unroll
            for (int r = 0; r < 4; ++r) {
                float h = fast_tanh(acc[rf][f][r]);
                acc[rf][f][r] = h;
                pk[r] = (short)bf16_rne(h);
            }
            *(short4v*)(&ht[16 * f + lr][rbase]) = pk;
        }
    }

    // GEMM2: u = sigmoid(h @ W2 + b2), A from ht (same wave's rows), B from global W2^T
    f32x4 uacc[2][8];
    #pragma unroll
    for (int f = 0; f < 8; ++f) {
        float bv = b2[16 * f + lr];
        f32x4 v = {bv, bv, bv, bv};
        uacc[0][f] = v; uacc[1][f] = v;
    }
    #pragma unroll
    for (int ks2 = 0; ks2 < 4; ++ks2) {
        short8 a2[2];
        #pragma unroll
        for (int rf = 0; rf < 2; ++rf) {
            const int rbl = wid * 32 + rf * 16 + lr;
            #pragma unroll
            for (int i = 0; i < 8; ++i)
                a2[rf][i] = (short)ht[ks2 * 32 + 8 * lg + i][rbl];
        }
        #pragma unroll
        for (int f = 0; f < 8; ++f) {
            const short8 bb = *(const short8*)(w2s + (16 * f + lr) * HID + ks2 * 32 + 8 * lg);
            uacc[0][f] = __builtin_amdgcn_mfma_f32_16x16x32_bf16(a2[0], bb, uacc[0][f], 0, 0, 0);
            uacc[1][f] = __builtin_amdgcn_mfma_f32_16x16x32_bf16(a2[1], bb, uacc[1][f], 0, 0, 0);
        }
    }
    #pragma unroll
    for (int rf = 0; rf < 2; ++rf)
        #pragma unroll
        for (int f = 0; f < 8; ++f)
            #pragma unroll
            for (int r = 0; r < 4; ++r)
                uacc[rf][f][r] = 1.0f / (1.0f + __expf(-uacc[rf][f][r]));

    // Mobius: per-row dots via 16-lane butterflies -> z = cA*h + cB*u
    float cA[2][4], cB[2][4];
    #pragma unroll
    for (int rf = 0; rf < 2; ++rf) {
        float hh[4] = {0,0,0,0}, uu[4] = {0,0,0,0}, hu[4] = {0,0,0,0};
        #pragma unroll
        for (int f = 0; f < 8; ++f)
            #pragma unroll
            for (int r = 0; r < 4; ++r) {
                float h = acc[rf][f][r], u = uacc[rf][f][r];
                hh[r] += h * h; uu[r] += u * u; hu[r] += h * u;
            }
        #pragma unroll
        for (int m = 1; m <= 8; m <<= 1)
            #pragma unroll
            for (int r = 0; r < 4; ++r) {
                hh[r] += __shfl_xor(hh[r], m);
                uu[r] += __shfl_xor(uu[r], m);
                hu[r] += __shfl_xor(hu[r], m);
            }
        #pragma unroll
        for (int r = 0; r < 4; ++r) {
            float nh = sqrtf(fmaxf(hh[r], 1e-14f));
            float nu = sqrtf(fmaxf(uu[r], 1e-14f));
            float argh = fminf(fmaxf(sc * nh, 1e-7f), 1.0f - 1e-5f);
            float argu = fminf(fmaxf(sc * nu, 1e-7f), 1.0f - 1e-5f);
            float ath = 0.5f * __logf((1.0f + argh) / (1.0f - argh));
            float atu = 0.5f * __logf((1.0f + argu) / (1.0f - argu));
            float alpha = fast_tanh(0.3f * ath) / (sc * nh);
            float beta  = fast_tanh(0.7f * atu) / (sc * nu);
            float UV = alpha * beta * hu[r];
            float UU = alpha * alpha * hh[r];
            float VV = beta * beta * uu[r];
            float den = fmaxf(1.0f + 2.0f * c * UV + c * c * UU * VV, 1e-7f);
            cA[rf][r] = (1.0f + 2.0f * c * UV + c * VV) * alpha / den;
            cB[rf][r] = (1.0f - c * UU) * beta / den;
        }
    }
    // write z (bf16) into ht, reusing wave-private rows
    #pragma unroll
    for (int rf = 0; rf < 2; ++rf) {
        const int rbase = wid * 32 + rf * 16 + 4 * lg;
        #pragma unroll
        for (int f = 0; f < 8; ++f) {
            short4v pk;
            #pragma unroll
            for (int r = 0; r < 4; ++r) {
                float z = cA[rf][r] * acc[rf][f][r] + cB[rf][r] * uacc[rf][f][r];
                pk[r] = (short)bf16_rne(z);
            }
            *(short4v*)(&ht[16 * f + lr][rbase]) = pk;
        }
    }

    // GEMM3: out = z @ W3 + ob via MFMA (cols padded to 16)
    float obv = (lr < OUT_DIM) ? ob[lr] : 0.0f;
    f32x4 oacc[2];
    oacc[0][0] = obv; oacc[0][1] = obv; oacc[0][2] = obv; oacc[0][3] = obv;
    oacc[1] = oacc[0];
    #pragma unroll
    for (int ks2 = 0; ks2 < 4; ++ks2) {
        short8 a3[2];
        #pragma unroll
        for (int rf = 0; rf < 2; ++rf) {
            const int rbl = wid * 32 + rf * 16 + lr;
            #pragma unroll
            for (int i = 0; i < 8; ++i)
                a3[rf][i] = (short)ht[ks2 * 32 + 8 * lg + i][rbl];
        }
        const short8 b3 = *(const short8*)(w3s + lr * HID + ks2 * 32 + 8 * lg);
        oacc[0] = __builtin_amdgcn_mfma_f32_16x16x32_bf16(a3[0], b3, oacc[0], 0, 0, 0);
        oacc[1] = __builtin_amdgcn_mfma_f32_16x16x32_bf16(a3[1], b3, oacc[1], 0, 0, 0);
    }
    if (lr < OUT_DIM) {
        #pragma unroll
        for (int rf = 0; rf < 2; ++rf) {
            const int rbase = row0 + wid * 32 + rf * 16 + 4 * lg;
            #pragma unroll
            for (int r = 0; r < 4; ++r)
                OUT[(size_t)(rbase + r) * OUT_DIM + lr] = oacc[rf][r];
        }
    }
}

extern "C" void kernel_launch(void* const* d_in, const int* in_sizes, int n_in,
                              void* d_out, int out_size, void* d_ws, size_t ws_size,
                              hipStream_t stream) {
    const float* X  = (const float*)d_in[0];
    const float* W1 = (const float*)d_in[1];
    const float* B1 = (const float*)d_in[2];
    const float* W2 = (const float*)d_in[3];
    const float* B2 = (const float*)d_in[4];
    const float* W3 = (const float*)d_in[5];
    const float* OB = (const float*)d_in[6];
    const float* CS = (const float*)d_in[7];
    unsigned short* w1h = (unsigned short*)((char*)d_ws + OFF_W1H);
    unsigned short* w1l = (unsigned short*)((char*)d_ws + OFF_W1L);
    unsigned short* w2s = (unsigned short*)((char*)d_ws + OFF_W2S);
    unsigned short* w3s = (unsigned short*)((char*)d_ws + OFF_W3S);
    prep_kernel<<<HID + 2, 256, 0, stream>>>(W1, W2, W3, w1h, w1l, w2s, w3s);
    fused_kernel<<<NBLK, 256, 0, stream>>>(X, B1, B2, OB, CS, w1h, w1l, w2s, w3s, (float*)d_out);
}

// Round 8
// 342.137 us; speedup vs baseline: 1.0439x; 1.0439x over previous
//
#include <hip/hip_runtime.h>

typedef __attribute__((ext_vector_type(8))) short short8;
typedef __attribute__((ext_vector_type(4))) short short4v;
typedef __attribute__((ext_vector_type(4))) float f32x4;

#define BATCH 65536
#define IN_DIM 784
#define HID 128
#define OUT_DIM 10
#define KPAD 800
#define NKS 25
#define BM 64
#define NBLK (BATCH / BM)   // 1024 blocks -> 4 blocks/CU -> 16 waves/CU

// workspace offsets (bytes), all 256-aligned
#define OFF_W1H 0
#define OFF_W1L 204800
#define OFF_W2S 409600
#define OFF_W3S 442368

__device__ __forceinline__ unsigned short bf16_rne(float f) {
    unsigned u = __float_as_uint(f);
    return (unsigned short)((u + 0x7FFFu + ((u >> 16) & 1u)) >> 16);
}
__device__ __forceinline__ float fast_tanh(float x) {
    float e = __expf(2.0f * x);
    return 1.0f - 2.0f / (e + 1.0f);
}

// Pre-pass: W1 -> k-padded (800), kstep-tiled [ks][col][32] bf16 hi/lo;
// W2 -> transposed [n][k] bf16; W3 -> transposed [j(pad16)][k] bf16.
__global__ void prep_kernel(const float* __restrict__ W1, const float* __restrict__ W2,
                            const float* __restrict__ W3,
                            unsigned short* __restrict__ w1h, unsigned short* __restrict__ w1l,
                            unsigned short* __restrict__ w2s, unsigned short* __restrict__ w3s) {
    int b = blockIdx.x, t = threadIdx.x;
    if (b < HID) {
        int col = b;
        for (int k = t; k < KPAD; k += 256) {
            float v = (k < IN_DIM) ? W1[k * HID + col] : 0.0f;
            unsigned u = __float_as_uint(v);
            unsigned short hi = (unsigned short)(u >> 16);       // trunc hi
            float hif = __uint_as_float(u & 0xFFFF0000u);
            unsigned short lo = bf16_rne(v - hif);               // rne lo
            int idx = ((k >> 5) * HID + col) * 32 + (k & 31);
            w1h[idx] = hi; w1l[idx] = lo;
        }
    } else if (b == HID) {
        for (int i = t; i < HID * HID; i += 256) {
            int n = i >> 7, k = i & 127;
            w2s[i] = bf16_rne(W2[k * HID + n]);
        }
    } else {
        for (int i = t; i < 16 * HID; i += 256) {
            int j = i >> 7, k = i & 127;
            float v = (j < OUT_DIM) ? W3[k * OUT_DIM + j] : 0.0f;
            w3s[i] = bf16_rne(v);
        }
    }
}

// BM=64: 4 waves/block, each wave owns 16 rows. 1024 blocks -> 4 blocks/CU
// (16 waves/CU) so cross-block overlap hides the per-block barrier drains
// (latency-bound fix for R6's 22% occupancy). W1 staged via LDS double-buffer
// (reg prefetch, 1 barrier/K-step); ht aliased onto the W1 buffers.
__launch_bounds__(256, 4)
__global__ void fused_kernel(const float* __restrict__ X,
                             const float* __restrict__ b1,
                             const float* __restrict__ b2,
                             const float* __restrict__ ob,
                             const float* __restrict__ csc,
                             const unsigned short* __restrict__ w1h,
                             const unsigned short* __restrict__ w1l,
                             const unsigned short* __restrict__ w2s,
                             const unsigned short* __restrict__ w3s,
                             float* __restrict__ OUT) {
    __shared__ unsigned short smem[2][2][HID][36];   // 36864 B -> 4 blocks/CU
    unsigned short (*ht)[72] = (unsigned short (*)[72])&smem[0][0][0][0]; // 18432 B alias

    const int t = threadIdx.x;
    const int wid = t >> 6, lane = t & 63;
    const int lg = lane >> 4, lr = lane & 15;
    const int row0 = blockIdx.x * BM;
    const int wrow = wid * 16;            // this wave's 16-row slice

    // GEMM1 accumulators init with bias1 (C/D layout: col=16f+lr, row=4*lg+r)
    f32x4 acc[8];
    #pragma unroll
    for (int f = 0; f < 8; ++f) {
        float bv = b1[16 * f + lr];
        f32x4 v = {bv, bv, bv, bv};
        acc[f] = v;
    }

    // x: lane loads its own A-fragment: row wrow+lr, k = ks*32+8*lg .. +8
    f32x4 xcur[2], xnxt[2];
    short8 wcur[4], wnxt[4];

    #define LOADX(dst, ks)                                                        \
        {                                                                         \
            int k0_ = (ks) * 32 + 8 * lg;                                         \
            f32x4 a_ = {0,0,0,0}, b_ = {0,0,0,0};                                 \
            if (k0_ < IN_DIM) {                                                   \
                const f32x4* p_ = (const f32x4*)(X +                              \
                    (size_t)(row0 + wrow + lr) * IN_DIM + k0_);                   \
                a_ = p_[0]; b_ = p_[1];                                           \
            }                                                                     \
            dst[0] = a_; dst[1] = b_;                                             \
        }
    #define LOADW(dst, ks)                                                        \
        {                                                                         \
            const short8* ph_ = (const short8*)(w1h + (ks) * 4096) + t * 2;       \
            const short8* pl_ = (const short8*)(w1l + (ks) * 4096) + t * 2;       \
            dst[0] = ph_[0]; dst[1] = ph_[1];                                     \
            dst[2] = pl_[0]; dst[3] = pl_[1];                                     \
        }

    LOADX(xcur, 0);
    LOADW(wcur, 0);

    for (int ks = 0; ks < NKS; ++ks) {
        const int cur = ks & 1;
        {   // ds_write staged W1 regs (thread t -> col t>>1, k (t&1)*16..+16)
            short8* dh = (short8*)&smem[cur][0][t >> 1][(t & 1) * 16];
            short8* dl = (short8*)&smem[cur][1][t >> 1][(t & 1) * 16];
            dh[0] = wcur[0]; dh[1] = wcur[1];
            dl[0] = wcur[2]; dl[1] = wcur[3];
        }
        if (ks + 1 < NKS) {   // issue next-tile loads; in flight until the barrier
            LOADX(xnxt, ks + 1);
            LOADW(wnxt, ks + 1);
        }
        __syncthreads();

        // split x into bf16 hi/lo in-register (trunc hi + rne lo)
        short8 xh, xl;
        #pragma unroll
        for (int j = 0; j < 8; ++j) {
            float v = (j < 4) ? xcur[0][j] : xcur[1][j - 4];
            unsigned u = __float_as_uint(v);
            xh[j] = (short)(u >> 16);
            float lof = v - __uint_as_float(u & 0xFFFF0000u);
            xl[j] = (short)(__float_as_uint(lof) >> 16);
        }
        // 3-pass split MFMA (24 MFMA / wave / K-step)
        #pragma unroll
        for (int f = 0; f < 8; ++f) {
            const short8 bh = *(const short8*)&smem[cur][0][16 * f + lr][8 * lg];
            const short8 bl = *(const short8*)&smem[cur][1][16 * f + lr][8 * lg];
            acc[f] = __builtin_amdgcn_mfma_f32_16x16x32_bf16(xh, bh, acc[f], 0, 0, 0);
            acc[f] = __builtin_amdgcn_mfma_f32_16x16x32_bf16(xl, bh, acc[f], 0, 0, 0);
            acc[f] = __builtin_amdgcn_mfma_f32_16x16x32_bf16(xh, bl, acc[f], 0, 0, 0);
        }
        // rotate prefetch regs
        xcur[0] = xnxt[0]; xcur[1] = xnxt[1];
        #pragma unroll
        for (int j = 0; j < 4; ++j) wcur[j] = wnxt[j];
    }
    __syncthreads();   // all waves done reading W1 buffers before ht alias write

    const float cs = csc[0];
    const float sgc = 1.0f / (1.0f + __expf(-cs));
    const float c = 0.001f * (0.5f + 1.5f * sgc);
    const float sc = sqrtf(c);

    // h = tanh(.), keep fp32 in acc; write bf16 transpose to ht (wave-private cols)
    {
        const int rbase = wrow + 4 * lg;
        #pragma unroll
        for (int f = 0; f < 8; ++f) {
            short4v pk;
            #pragma unroll
            for (int r = 0; r < 4; ++r) {
                float h = fast_tanh(acc[f][r]);
                acc[f][r] = h;
                pk[r] = (short)bf16_rne(h);
            }
            *(short4v*)(&ht[16 * f + lr][rbase]) = pk;
        }
    }

    // GEMM2: u = sigmoid(h @ W2 + b2), A from ht (own wave's cols), B from w2s (L2)
    f32x4 uacc[8];
    #pragma unroll
    for (int f = 0; f < 8; ++f) {
        float bv = b2[16 * f + lr];
        f32x4 v = {bv, bv, bv, bv};
        uacc[f] = v;
    }
    #pragma unroll
    for (int ks2 = 0; ks2 < 4; ++ks2) {
        short8 a2;
        const int rbl = wrow + lr;
        #pragma unroll
        for (int i = 0; i < 8; ++i)
            a2[i] = (short)ht[ks2 * 32 + 8 * lg + i][rbl];
        #pragma unroll
        for (int f = 0; f < 8; ++f) {
            const short8 bb = *(const short8*)(w2s + (16 * f + lr) * HID + ks2 * 32 + 8 * lg);
            uacc[f] = __builtin_amdgcn_mfma_f32_16x16x32_bf16(a2, bb, uacc[f], 0, 0, 0);
        }
    }
    #pragma unroll
    for (int f = 0; f < 8; ++f)
        #pragma unroll
        for (int r = 0; r < 4; ++r)
            uacc[f][r] = 1.0f / (1.0f + __expf(-uacc[f][r]));

    // Mobius: per-row dots via 16-lane butterflies -> z = cA*h + cB*u
    float cA[4], cB[4];
    {
        float hh[4] = {0,0,0,0}, uu[4] = {0,0,0,0}, hu[4] = {0,0,0,0};
        #pragma unroll
        for (int f = 0; f < 8; ++f)
            #pragma unroll
            for (int r = 0; r < 4; ++r) {
                float h = acc[f][r], u = uacc[f][r];
                hh[r] += h * h; uu[r] += u * u; hu[r] += h * u;
            }
        #pragma unroll
        for (int m = 1; m <= 8; m <<= 1)
            #pragma unroll
            for (int r = 0; r < 4; ++r) {
                hh[r] += __shfl_xor(hh[r], m);
                uu[r] += __shfl_xor(uu[r], m);
                hu[r] += __shfl_xor(hu[r], m);
            }
        #pragma unroll
        for (int r = 0; r < 4; ++r) {
            float nh = sqrtf(fmaxf(hh[r], 1e-14f));
            float nu = sqrtf(fmaxf(uu[r], 1e-14f));
            float argh = fminf(fmaxf(sc * nh, 1e-7f), 1.0f - 1e-5f);
            float argu = fminf(fmaxf(sc * nu, 1e-7f), 1.0f - 1e-5f);
            float ath = 0.5f * __logf((1.0f + argh) / (1.0f - argh));
            float atu = 0.5f * __logf((1.0f + argu) / (1.0f - argu));
            float alpha = fast_tanh(0.3f * ath) / (sc * nh);
            float beta  = fast_tanh(0.7f * atu) / (sc * nu);
            float UV = alpha * beta * hu[r];
            float UU = alpha * alpha * hh[r];
            float VV = beta * beta * uu[r];
            float den = fmaxf(1.0f + 2.0f * c * UV + c * c * UU * VV, 1e-7f);
            cA[r] = (1.0f + 2.0f * c * UV + c * VV) * alpha / den;
            cB[r] = (1.0f - c * UU) * beta / den;
        }
    }
    // write z (bf16) into ht (same wave-private cols)
    {
        const int rbase = wrow + 4 * lg;
        #pragma unroll
        for (int f = 0; f < 8; ++f) {
            short4v pk;
            #pragma unroll
            for (int r = 0; r < 4; ++r) {
                float z = cA[r] * acc[f][r] + cB[r] * uacc[f][r];
                pk[r] = (short)bf16_rne(z);
            }
            *(short4v*)(&ht[16 * f + lr][rbase]) = pk;
        }
    }

    // GEMM3: out = z @ W3 + ob via MFMA (cols padded to 16)
    float obv = (lr < OUT_DIM) ? ob[lr] : 0.0f;
    f32x4 oacc = {obv, obv, obv, obv};
    #pragma unroll
    for (int ks2 = 0; ks2 < 4; ++ks2) {
        short8 a3;
        const int rbl = wrow + lr;
        #pragma unroll
        for (int i = 0; i < 8; ++i)
            a3[i] = (short)ht[ks2 * 32 + 8 * lg + i][rbl];
        const short8 b3 = *(const short8*)(w3s + lr * HID + ks2 * 32 + 8 * lg);
        oacc = __builtin_amdgcn_mfma_f32_16x16x32_bf16(a3, b3, oacc, 0, 0, 0);
    }
    if (lr < OUT_DIM) {
        const int rbase = row0 + wrow + 4 * lg;
        #pragma unroll
        for (int r = 0; r < 4; ++r)
            OUT[(size_t)(rbase + r) * OUT_DIM + lr] = oacc[r];
    }
}

extern "C" void kernel_launch(void* const* d_in, const int* in_sizes, int n_in,
                              void* d_out, int out_size, void* d_ws, size_t ws_size,
                              hipStream_t stream) {
    const float* X  = (const float*)d_in[0];
    const float* W1 = (const float*)d_in[1];
    const float* B1 = (const float*)d_in[2];
    const float* W2 = (const float*)d_in[3];
    const float* B2 = (const float*)d_in[4];
    const float* W3 = (const float*)d_in[5];
    const float* OB = (const float*)d_in[6];
    const float* CS = (const float*)d_in[7];
    unsigned short* w1h = (unsigned short*)((char*)d_ws + OFF_W1H);
    unsigned short* w1l = (unsigned short*)((char*)d_ws + OFF_W1L);
    unsigned short* w2s = (unsigned short*)((char*)d_ws + OFF_W2S);
    unsigned short* w3s = (unsigned short*)((char*)d_ws + OFF_W3S);
    prep_kernel<<<HID + 2, 256, 0, stream>>>(W1, W2, W3, w1h, w1l, w2s, w3s);
    fused_kernel<<<NBLK, 256, 0, stream>>>(X, B1, B2, OB, CS, w1h, w1l, w2s, w3s, (float*)d_out);
}